// Round 1
// baseline (282.797 us; speedup 1.0000x reference)
//
#include <hip/hip_runtime.h>

// QuantizedBottleneck via i8 MFMA implicit GEMM. Exact integer math.
//   prep  : pack all MFMA A-fragments (w1/w2/w3 -> i8) into d_ws
//   conv1 : 1x1 256->64 + bn1 -> t1 [n][64] i8   (dwordx4 staging, reg dbuf)
//   conv23: fused 3x3 64->64 pad1 + bn2 -> LDS, then 1x1 64->256 + bn3 +
//           residual add -> out int32. 2-row tiles, grid (28,32).
//           t2 never touches global memory.
// t1 holds (q - zin2) so zero-padding == zero bytes; LDS t2 holds (q - zin3).
// MFMA 16x16x64_i8: A[m=lane&15][k=(lane>>4)*16+j], B[k][n=lane&15],
// C/D: col=lane&15, row=(lane>>4)*4+reg.

typedef int v4i __attribute__((ext_vector_type(4)));

#define BATCH 32
#define CIN 256
#define CMID 64
#define HW 3136
#define W56 56

#define T1_BYTES ((size_t)BATCH * HW * CMID)
#define WP_BYTES ((size_t)68 * 64 * 16)

__device__ __forceinline__ int requant_q(int acc, int M0, int shift, int zout) {
    long long prod = (long long)acc * (long long)M0;
    long long nudge = (prod >= 0) ? (1LL << 30) : (1LL - (1LL << 30));
    long long hi = (prod + nudge) >> 31;
    long long r = (hi + (1LL << (shift - 1))) >> shift;
    int v = (int)r + zout;
    return v < 0 ? 0 : (v > 255 ? 255 : v);
}

__device__ __forceinline__ long long mulshift_ll(long long v, int M0, int shift) {
    long long prod = v * (long long)M0;
    long long nudge = (prod >= 0) ? (1LL << 30) : (1LL - (1LL << 30));
    long long hi = (prod + nudge) >> 31;
    return (hi + (1LL << (shift - 1))) >> shift;
}

__device__ __forceinline__ v4i pack16f(const float* src, int stride) {
    v4i r;
#pragma unroll
    for (int d = 0; d < 4; ++d) {
        unsigned int u = 0;
#pragma unroll
        for (int by = 0; by < 4; ++by) {
            int v = (int)src[(d * 4 + by) * stride];
            u |= ((unsigned int)(v & 255)) << (8 * by);
        }
        r[d] = (int)u;
    }
    return r;
}

// -------- prep: fragsets w1 [0,16), w2 [16,52), w3 [52,68) -------------------
__global__ __launch_bounds__(256) void k_prep(
    const float* __restrict__ w1, const float* __restrict__ w2,
    const float* __restrict__ w3, v4i* __restrict__ wp)
{
    int id = blockIdx.x * 256 + threadIdx.x;
    int fid = id >> 6, lane = id & 63;
    if (fid >= 68) return;
    int col = lane & 15, ci0 = (lane >> 4) * 16;
    const float* src;
    int stride;
    if (fid < 16) {
        int wv = fid >> 2, ks = fid & 3;
        src = w1 + (size_t)(wv * 16 + col) * 256 + ks * 64 + ci0;
        stride = 1;
    } else if (fid < 52) {
        int i = fid - 16, wv = i / 9, t = i - wv * 9;
        src = w2 + ((size_t)(wv * 16 + col) * 64 + ci0) * 9 + t;
        stride = 9;
    } else {
        int s = fid - 52;
        src = w3 + (size_t)(s * 16 + col) * 64 + ci0;
        stride = 1;
    }
    wp[fid * 64 + lane] = pack16f(src, stride);
}

// -------- conv1: 1x1 256->64 + bn1 -> t1 ------------------------------------
// grid (28, 32): row-pair x batch; tile = 112 pixels (1 row-pair, one b).
// Staging: thread (cg=tid&7, q=tid>>3, active q<28) loads 8 int4 (4 px, 8 ci)
// per K-step, packs to i8, b64 LDS writes (conflict-free). Register dbuf.
__global__ __launch_bounds__(256, 4) void k_conv1(
    const int* __restrict__ x, const v4i* __restrict__ wp1,
    const float* __restrict__ bn_w, const float* __restrict__ bn_b,
    const int* __restrict__ conv_zin, const int* __restrict__ conv_m0,
    const int* __restrict__ conv_shift, const int* __restrict__ conv_zout,
    const int* __restrict__ bn_m0, const int* __restrict__ bn_shift,
    const int* __restrict__ bn_zout, signed char* __restrict__ t1)
{
    __shared__ v4i sm[560];                        // 112 px x 80 B
    const int tid = threadIdx.x, lane = tid & 63, wv = tid >> 6;
    const int col = lane & 15, koff = lane >> 4;
    const int b = blockIdx.y;
    const int hw0 = blockIdx.x * 112;
    const int co0 = wv * 16;

    v4i a[4];
#pragma unroll
    for (int ks = 0; ks < 4; ++ks) a[ks] = wp1[(wv * 4 + ks) * 64 + lane];

    const int cg = tid & 7, q = tid >> 3;
    const bool act = q < 28;
    const int zin = conv_zin[0];
    const int* xbase = x + (size_t)b * CIN * HW + hw0 + 4 * q;

    v4i xa[8], xa2[8];
    if (act) {
#pragma unroll
        for (int j = 0; j < 8; ++j)
            xa[j] = *(const v4i*)(xbase + (size_t)(cg * 8 + j) * HW);
    }

    v4i acc[7];
#pragma unroll
    for (int i = 0; i < 7; ++i) acc[i] = (v4i){0, 0, 0, 0};

    unsigned long long* smu = (unsigned long long*)sm;
#pragma unroll
    for (int ks = 0; ks < 4; ++ks) {
        if (ks) __syncthreads();                   // prior MFMA reads done
        if (act) {
#pragma unroll
            for (int p = 0; p < 4; ++p) {
                unsigned int lo = 0, hi = 0;
#pragma unroll
                for (int j = 0; j < 4; ++j) {
                    lo |= ((unsigned int)((xa[j][p] - zin) & 255)) << (8 * j);
                    hi |= ((unsigned int)((xa[j + 4][p] - zin) & 255)) << (8 * j);
                }
                smu[(q * 4 + p) * 10 + cg] = ((unsigned long long)hi << 32) | lo;
            }
        }
        __syncthreads();
        if (ks < 3 && act) {                       // prefetch next K-step
#pragma unroll
            for (int j = 0; j < 8; ++j)
                xa2[j] = *(const v4i*)(xbase + (size_t)((ks + 1) * 64 + cg * 8 + j) * HW);
        }
#pragma unroll
        for (int nt = 0; nt < 7; ++nt) {
            v4i bf = sm[(nt * 16 + col) * 5 + koff];
            acc[nt] = __builtin_amdgcn_mfma_i32_16x16x64_i8(a[ks], bf, acc[nt], 0, 0, 0);
        }
        if (ks < 3) {
#pragma unroll
            for (int j = 0; j < 8; ++j) xa[j] = xa2[j];
        }
    }

    const int cm0 = conv_m0[0], csh = conv_shift[0], czo = conv_zout[0];
    const int bm0 = bn_m0[0], bsh = bn_shift[0], bzo = bn_zout[0];
    const int zin2 = conv_zin[1];
    const int rowb = koff * 4;
    int bw[4], bb[4];
#pragma unroll
    for (int r = 0; r < 4; ++r) {
        bw[r] = (int)bn_w[co0 + rowb + r];
        bb[r] = (int)bn_b[co0 + rowb + r];
    }
#pragma unroll
    for (int nt = 0; nt < 7; ++nt) {
        int n = b * HW + hw0 + nt * 16 + col;
        unsigned int pkd = 0;
#pragma unroll
        for (int r = 0; r < 4; ++r) {
            int qv = requant_q(acc[nt][r], cm0, csh, czo);
            int a2 = (qv - czo) * bw[r] + bb[r];
            int q2 = requant_q(a2, bm0, bsh, bzo);
            pkd |= ((unsigned int)((q2 - zin2) & 255)) << (8 * r);
        }
        *(unsigned int*)(t1 + (size_t)n * 64 + co0 + rowb) = pkd;
    }
}

// -------- conv23: fused 3x3 64->64 + bn2 (-> LDS) then 1x1 64->256 + bn3 ----
//          + residual add -> out int32.  grid (28, 32): 2 output rows x batch.
// Phase A: conv2 on 112 px (4 halo rows in sm), requant+bn2 -> t2s LDS in
//          B-fragment layout (pix*5 + part padded v4i).
// Phase B: 4 fragset steps; wave wv owns out-ch [(wv*4+s)*16, +16).
//          Residual x loads issued BEFORE the MFMAs of each step.
__global__ __launch_bounds__(256, 3) void k_conv23(
    const signed char* __restrict__ t1, const v4i* __restrict__ wp2,
    const v4i* __restrict__ wp3,
    const float* __restrict__ bn2_w, const float* __restrict__ bn2_b,
    const float* __restrict__ bn3_w, const float* __restrict__ bn3_b,
    const int* __restrict__ x,
    const int* __restrict__ conv_zin, const int* __restrict__ conv_m0,
    const int* __restrict__ conv_shift, const int* __restrict__ conv_zout,
    const int* __restrict__ bn_m0, const int* __restrict__ bn_shift,
    const int* __restrict__ bn_zout,
    const int* __restrict__ add_z, const int* __restrict__ add_m0,
    const int* __restrict__ add_shift, const int* __restrict__ add_zout,
    int* __restrict__ out)
{
    __shared__ v4i sm[1120];                      // 224 px (4 halo rows) x 80 B
    __shared__ v4i t2s[560];                      // 112 px x 80 B (conv2 out)
    const int tid = threadIdx.x, lane = tid & 63, wv = tid >> 6;
    const int col = lane & 15, koff = lane >> 4;
    const int b = blockIdx.y;
    const int r0 = blockIdx.x * 2;
    const int co0 = wv * 16;
    const int rowb = koff * 4;

    v4i a[9];
#pragma unroll
    for (int t = 0; t < 9; ++t) a[t] = wp2[(wv * 9 + t) * 64 + lane];

    const v4i* t1v = (const v4i*)t1;
#pragma unroll
    for (int k = 0; k < 4; ++k) {
        int idx = tid + k * 256;
        if (idx < 896) {                          // 224 px x 4 parts
            int pixl = idx >> 2, part = idx & 3;
            int lrow = pixl / W56, gw = pixl - lrow * W56;
            int grow = r0 - 1 + lrow;
            v4i v = (v4i){0, 0, 0, 0};
            if ((unsigned)grow < 56u)
                v = t1v[((size_t)b * HW + grow * W56 + gw) * 4 + part];
            sm[pixl * 5 + part] = v;
        }
    }
    __syncthreads();

    int orow[7], wc[7];
#pragma unroll
    for (int nt = 0; nt < 7; ++nt) {
        int pix = nt * 16 + col;
        orow[nt] = pix / W56;
        wc[nt] = pix - orow[nt] * W56;
    }

    v4i acc[7];
#pragma unroll
    for (int i = 0; i < 7; ++i) acc[i] = (v4i){0, 0, 0, 0};

#pragma unroll
    for (int kh = 0; kh < 3; ++kh) {
#pragma unroll
        for (int kw = 0; kw < 3; ++kw) {
            v4i af = a[kh * 3 + kw];
#pragma unroll
            for (int nt = 0; nt < 7; ++nt) {
                int sr = orow[nt] + kh;
                int sw = wc[nt] + kw - 1;
                bool valid = (unsigned)sw < 56u;
                v4i bf = sm[(sr * W56 + (valid ? sw : 0)) * 5 + koff];
                if (!valid) { bf[0] = 0; bf[1] = 0; bf[2] = 0; bf[3] = 0; }
                acc[nt] = __builtin_amdgcn_mfma_i32_16x16x64_i8(af, bf, acc[nt], 0, 0, 0);
            }
        }
    }

    {   // phase A epilogue: requant + bn2, pack -> t2s (B-frag layout)
        const int cm0 = conv_m0[1], csh = conv_shift[1], czo = conv_zout[1];
        const int bm0 = bn_m0[1], bsh = bn_shift[1], bzo = bn_zout[1];
        const int zin3 = conv_zin[2];
        int bw[4], bb[4];
#pragma unroll
        for (int r = 0; r < 4; ++r) {
            bw[r] = (int)bn2_w[co0 + rowb + r];
            bb[r] = (int)bn2_b[co0 + rowb + r];
        }
#pragma unroll
        for (int nt = 0; nt < 7; ++nt) {
            int pix = nt * 16 + col;
            unsigned int pkd = 0;
#pragma unroll
            for (int r = 0; r < 4; ++r) {
                int qv = requant_q(acc[nt][r], cm0, csh, czo);
                int a2 = (qv - czo) * bw[r] + bb[r];
                int q2 = requant_q(a2, bm0, bsh, bzo);
                pkd |= ((unsigned int)((q2 - zin3) & 255)) << (8 * r);
            }
            // channel bytes [wv*16+koff*4, +4) of pixel pix
            *(unsigned int*)((char*)t2s + (size_t)(pix * 5 + wv) * 16 + koff * 4) = pkd;
        }
    }
    __syncthreads();

    // ---- phase B: 1x1 64->256 + bn3 + residual add ----
    const int cm0 = conv_m0[2], csh = conv_shift[2], czo = conv_zout[2];
    const int bm0 = bn_m0[2], bsh = bn_shift[2], bzo = bn_zout[2];
    const int az0 = add_z[0], az1 = add_z[1];
    const int am0 = add_m0[0], am1 = add_m0[1];
    const int ash0 = add_shift[0], ash1 = add_shift[1];
    const int azout = add_zout[0];
    const int phw0 = r0 * W56;

#pragma unroll
    for (int s = 0; s < 4; ++s) {
        const int c0 = (wv * 4 + s) * 16;         // fragset wv*4+s
        v4i a3 = wp3[(wv * 4 + s) * 64 + lane];

        // hoist residual x loads so they overlap the MFMAs
        int xv[7][4];
#pragma unroll
        for (int nt = 0; nt < 7; ++nt) {
            int phw = phw0 + nt * 16 + col;
#pragma unroll
            for (int r = 0; r < 4; ++r)
                xv[nt][r] = x[((size_t)b * CIN + c0 + rowb + r) * HW + phw];
        }

        v4i acc3[7];
#pragma unroll
        for (int i = 0; i < 7; ++i) acc3[i] = (v4i){0, 0, 0, 0};
#pragma unroll
        for (int nt = 0; nt < 7; ++nt) {
            v4i bf = t2s[(nt * 16 + col) * 5 + koff];
            acc3[nt] = __builtin_amdgcn_mfma_i32_16x16x64_i8(a3, bf, acc3[nt], 0, 0, 0);
        }

        int bw3[4], bb3[4];
#pragma unroll
        for (int r = 0; r < 4; ++r) {
            bw3[r] = (int)bn3_w[c0 + rowb + r];
            bb3[r] = (int)bn3_b[c0 + rowb + r];
        }
#pragma unroll
        for (int nt = 0; nt < 7; ++nt) {
            int phw = phw0 + nt * 16 + col;
#pragma unroll
            for (int r = 0; r < 4; ++r) {
                int qv = requant_q(acc3[nt][r], cm0, csh, czo);
                int a2 = (qv - czo) * bw3[r] + bb3[r];
                int q2 = requant_q(a2, bm0, bsh, bzo);
                long long ra = mulshift_ll((long long)(xv[nt][r] - az0), am0, ash0);
                long long rb = mulshift_ll((long long)(q2 - az1), am1, ash1);
                int res = (int)(ra + rb) + azout;
                res = res < 0 ? 0 : (res > 255 ? 255 : res);
                out[((size_t)b * CIN + c0 + rowb + r) * HW + phw] = res;
            }
        }
    }
}

extern "C" void kernel_launch(void* const* d_in, const int* in_sizes, int n_in,
                              void* d_out, int out_size, void* d_ws, size_t ws_size,
                              hipStream_t stream) {
    const int* x = (const int*)d_in[0];
    const float* w1 = (const float*)d_in[1];
    const float* w2 = (const float*)d_in[2];
    const float* w3 = (const float*)d_in[3];
    const float* bn1_w = (const float*)d_in[4];
    const float* bn1_b = (const float*)d_in[5];
    const float* bn2_w = (const float*)d_in[6];
    const float* bn2_b = (const float*)d_in[7];
    const float* bn3_w = (const float*)d_in[8];
    const float* bn3_b = (const float*)d_in[9];
    const int* conv_zin = (const int*)d_in[10];
    const int* conv_m0 = (const int*)d_in[11];
    const int* conv_shift = (const int*)d_in[12];
    const int* conv_zout = (const int*)d_in[13];
    const int* bn_m0 = (const int*)d_in[14];
    const int* bn_shift = (const int*)d_in[15];
    const int* bn_zout = (const int*)d_in[16];
    const int* add_z = (const int*)d_in[17];
    const int* add_m0 = (const int*)d_in[18];
    const int* add_shift = (const int*)d_in[19];
    const int* add_zout = (const int*)d_in[20];

    v4i* wp = (v4i*)d_ws;
    signed char* t1 = (signed char*)d_ws + WP_BYTES;

    const v4i* wp1 = wp;
    const v4i* wp2 = wp + 16 * 64;
    const v4i* wp3 = wp + 52 * 64;

    k_prep<<<dim3(17), dim3(256), 0, stream>>>(w1, w2, w3, wp);
    k_conv1<<<dim3(28, 32), dim3(256), 0, stream>>>(x, wp1, bn1_w, bn1_b,
        conv_zin, conv_m0, conv_shift, conv_zout, bn_m0, bn_shift, bn_zout, t1);
    k_conv23<<<dim3(28, 32), dim3(256), 0, stream>>>(t1, wp2, wp3,
        bn2_w, bn2_b, bn3_w, bn3_b, x,
        conv_zin, conv_m0, conv_shift, conv_zout, bn_m0, bn_shift, bn_zout,
        add_z, add_m0, add_shift, add_zout, (int*)d_out);
}